// Round 1
// baseline (89.854 us; speedup 1.0000x reference)
//
#include <hip/hip_runtime.h>
#include <hip/hip_bf16.h>

#define NNODES 1365
#define FDIM 512
#define CDIM 64
#define NLEAF 1024
#define MAT (FDIM * CDIM)        /* 32768 floats per node */
#define OUT_LOGITS (NLEAF * CDIM) /* 65536 */

// ---------------------------------------------------------------------------
// Kernel 1: fused  (a) regularization reduction over deltas
//                  (b) per-node GEMM  X_desc[Lt,512] @ delta[512,64] -> logits
// One block per (node, leaf-tile of <=64 leaves).  1392 blocks, 256 threads.
// Streams the node's 128KB delta in 8 chunks of [64f x 64c] through LDS.
// ---------------------------------------------------------------------------
__global__ __launch_bounds__(256) void k_main(const float* __restrict__ x,
                                              const float* __restrict__ deltas,
                                              const float* __restrict__ heights,
                                              float* __restrict__ out)
{
    __shared__ float d_lds[64 * 64];   // delta chunk [f][c], 16 KB
    __shared__ float x_lds[64 * 68];   // x chunk [b][f], padded stride 68, 17 KB
    __shared__ float red[256];

    const int bid = blockIdx.x;
    const int tid = threadIdx.x;

    // ---- block -> (node, leaf tile) mapping (complete 4-ary tree, depth 5)
    int node, Lt, b0;
    bool tile0;
    if (bid < 16)       { node = 0;                     Lt = 64; b0 = bid * 64;                       tile0 = (bid == 0); }
    else if (bid < 32)  { int r = bid - 16; int j = r >> 2;
                          node = 1 + j;                 Lt = 64; b0 = j * 256 + (r & 3) * 64;         tile0 = ((r & 3) == 0); }
    else if (bid < 48)  { int j = bid - 32;  node = 5 + j;    Lt = 64; b0 = j * 64; tile0 = true; }
    else if (bid < 112) { int j = bid - 48;  node = 21 + j;   Lt = 16; b0 = j * 16; tile0 = true; }
    else if (bid < 368) { int j = bid - 112; node = 85 + j;   Lt = 4;  b0 = j * 4;  tile0 = true; }
    else                { int j = bid - 368; node = 341 + j;  Lt = 1;  b0 = j;      tile0 = true; }

    const float* dbase = deltas + (size_t)node * MAT;
    const bool isroot = (node == 0);

    const int ci = tid & 15;   // c-quad id  (c = 4*ci .. 4*ci+3)
    const int bi = tid >> 4;   // 0..15; thread covers rows {bi, bi+16, bi+32, bi+48} < Lt
    const int cq = ci * 4;

    bool act[4];
#pragma unroll
    for (int k = 0; k < 4; ++k) act[k] = (bi + 16 * k) < Lt;

    float acc[4][4];
#pragma unroll
    for (int k = 0; k < 4; ++k)
#pragma unroll
        for (int c = 0; c < 4; ++c) acc[k][c] = 0.f;

    float rsum = 0.f;

    for (int f0 = 0; f0 < FDIM; f0 += 64) {
        __syncthreads();
        // ---- stage delta chunk (global -> reg -> LDS), fold reg-reduction in
#pragma unroll
        for (int q = 0; q < 4; ++q) {
            const int flat = (q * 256 + tid) * 4;          // 0..4092
            const float4 v = *(const float4*)(dbase + f0 * 64 + flat);
            *(float4*)(d_lds + flat) = v;
            if (tile0) {
                if (isroot) rsum += v.x * v.x + v.y * v.y + v.z * v.z + v.w * v.w;
                else        rsum += fabsf(v.x) + fabsf(v.y) + fabsf(v.z) + fabsf(v.w);
            }
        }
        // ---- stage x chunk rows [b0, b0+Lt) x cols [f0, f0+64)
#pragma unroll
        for (int q = 0; q < 4; ++q) {
            const int row = q * 16 + bi;                   // 0..63
            if (row < Lt) {
                const float4 v = *(const float4*)(x + (size_t)(b0 + row) * FDIM + f0 + cq);
                *(float4*)(x_lds + row * 68 + cq) = v;
            }
        }
        __syncthreads();
        // ---- register-tiled GEMM on the chunk
#pragma unroll 4
        for (int fq = 0; fq < 16; ++fq) {
            const int f = fq * 4;
            const float4 d0 = *(const float4*)(d_lds + (f + 0) * 64 + cq);
            const float4 d1 = *(const float4*)(d_lds + (f + 1) * 64 + cq);
            const float4 d2 = *(const float4*)(d_lds + (f + 2) * 64 + cq);
            const float4 d3 = *(const float4*)(d_lds + (f + 3) * 64 + cq);
#pragma unroll
            for (int k = 0; k < 4; ++k) {
                if (!act[k]) continue;
                const float4 xv = *(const float4*)(x_lds + (bi + 16 * k) * 68 + f);
                acc[k][0] += xv.x * d0.x + xv.y * d1.x + xv.z * d2.x + xv.w * d3.x;
                acc[k][1] += xv.x * d0.y + xv.y * d1.y + xv.z * d2.y + xv.w * d3.y;
                acc[k][2] += xv.x * d0.z + xv.y * d1.z + xv.z * d2.z + xv.w * d3.z;
                acc[k][3] += xv.x * d0.w + xv.y * d1.w + xv.z * d2.w + xv.w * d3.w;
            }
        }
    }

    // ---- accumulate this node's contribution into logits
#pragma unroll
    for (int k = 0; k < 4; ++k) {
        if (!act[k]) continue;
        const int row = b0 + bi + 16 * k;
        float* o = out + (size_t)row * CDIM + cq;
        atomicAdd(o + 0, acc[k][0]);
        atomicAdd(o + 1, acc[k][1]);
        atomicAdd(o + 2, acc[k][2]);
        atomicAdd(o + 3, acc[k][3]);
    }

    // ---- regularization: block-reduce rsum, one atomic per node
    __syncthreads();
    red[tid] = tile0 ? rsum : 0.f;
    __syncthreads();
    for (int s = 128; s > 0; s >>= 1) {
        if (tid < s) red[tid] += red[tid + s];
        __syncthreads();
    }
    if (tid == 0 && tile0) {
        float scale = 1.0f;
        if (!isroot) {
            const int p = (node - 1) >> 2;
            float dist = fabsf(heights[node] - heights[p]);
            dist = fmaxf(dist, 1e-7f);
            scale = 1.0f / dist;
        }
        atomicAdd(out + OUT_LOGITS, red[0] * scale);
    }
}

// ---------------------------------------------------------------------------
// Kernel 2: in-place softmax over C=64 per leaf row. One 64-lane wave per row.
// ---------------------------------------------------------------------------
__global__ __launch_bounds__(256) void k_softmax(float* __restrict__ out)
{
    const int b = blockIdx.x * 4 + (threadIdx.x >> 6);
    const int c = threadIdx.x & 63;
    const float v = out[(size_t)b * CDIM + c];
    float m = v;
#pragma unroll
    for (int off = 32; off > 0; off >>= 1) m = fmaxf(m, __shfl_xor(m, off, 64));
    const float e = expf(v - m);
    float s = e;
#pragma unroll
    for (int off = 32; off > 0; off >>= 1) s += __shfl_xor(s, off, 64);
    out[(size_t)b * CDIM + c] = e / s;
}

extern "C" void kernel_launch(void* const* d_in, const int* in_sizes, int n_in,
                              void* d_out, int out_size, void* d_ws, size_t ws_size,
                              hipStream_t stream)
{
    const float* x       = (const float*)d_in[0];
    const float* deltas  = (const float*)d_in[1];
    const float* heights = (const float*)d_in[2];
    // anc / parent / leaf_ids (d_in[3..5]) are implied by the static tree shape.
    float* out = (float*)d_out;

    // zero logits + reg scalar (atomically accumulated below)
    hipMemsetAsync(out, 0, (size_t)(OUT_LOGITS + 1) * sizeof(float), stream);

    k_main<<<1392, 256, 0, stream>>>(x, deltas, heights, out);
    k_softmax<<<NLEAF / 4, 256, 0, stream>>>(out);
}

// Round 2
// 64.113 us; speedup vs baseline: 1.4015x; 1.4015x over previous
//
#include <hip/hip_runtime.h>
#include <hip/hip_bf16.h>

#define FDIM 512
#define CDIM 64
#define NLEAF 1024
#define MAT (FDIM * CDIM)          /* 32768 floats per node */
#define OUT_LOGITS (NLEAF * CDIM)  /* 65536 */

// ---------------------------------------------------------------------------
// Fused kernel: streams each node's delta[512][64] ONCE from global memory
// (coalesced float4 along C, no LDS staging of deltas), FMA-ing directly
// against R broadcast x-rows from LDS. Folds the regularization reduction
// into the same pass. One block = (node, leaf-tile of R rows).
//   R=16 : depths 0..3  (256 blocks)
//   R=4  : depth 4      (256 blocks)
//   R=1  : leaves       (1024 blocks)
// Thread layout: tid = fg*16 + cq;  fg=tid>>4 (16 f-groups of 32 f),
// cq=tid&15 (c-quad -> 4 consecutive c). Lanes 0..15 of a wave are one
// f-group's 16 c-quads -> each global load instruction covers a contiguous
// 256B row segment of delta.
// ---------------------------------------------------------------------------
template<int R>
__device__ __forceinline__ void run_tile(const float* __restrict__ x,
                                         const float* __restrict__ deltas,
                                         const float* __restrict__ heights,
                                         float* __restrict__ out,
                                         int node, int b0, bool regblk,
                                         float* lds, int tid)
{
    const int w  = tid >> 6;          // wave 0..3
    const int cq = tid & 15;          // c-quad
    const int fb = (tid >> 4) * 32;   // this thread's f-slice base (32 f)
    const float* dbase = deltas + (size_t)node * MAT;
    const bool isroot = (node == 0);

    // ---- stage x rows [b0, b0+R) into LDS (R*512 floats)
    for (int idx = tid; idx < R * 128; idx += 256) {
        const int r = idx >> 7, fq = idx & 127;
        *(float4*)(lds + r * FDIM + fq * 4) =
            *(const float4*)(x + (size_t)(b0 + r) * FDIM + fq * 4);
    }
    __syncthreads();

    float4 acc[R];
#pragma unroll
    for (int r = 0; r < R; ++r) acc[r] = make_float4(0.f, 0.f, 0.f, 0.f);
    float rsum = 0.f;

#pragma unroll
    for (int ii = 0; ii < 8; ++ii) {
        const int f0 = fb + ii * 4;
        const float4 d0 = *(const float4*)(dbase + (size_t)(f0 + 0) * CDIM + cq * 4);
        const float4 d1 = *(const float4*)(dbase + (size_t)(f0 + 1) * CDIM + cq * 4);
        const float4 d2 = *(const float4*)(dbase + (size_t)(f0 + 2) * CDIM + cq * 4);
        const float4 d3 = *(const float4*)(dbase + (size_t)(f0 + 3) * CDIM + cq * 4);
        if (regblk) {
            if (isroot) {
                rsum += d0.x*d0.x + d0.y*d0.y + d0.z*d0.z + d0.w*d0.w;
                rsum += d1.x*d1.x + d1.y*d1.y + d1.z*d1.z + d1.w*d1.w;
                rsum += d2.x*d2.x + d2.y*d2.y + d2.z*d2.z + d2.w*d2.w;
                rsum += d3.x*d3.x + d3.y*d3.y + d3.z*d3.z + d3.w*d3.w;
            } else {
                rsum += fabsf(d0.x) + fabsf(d0.y) + fabsf(d0.z) + fabsf(d0.w);
                rsum += fabsf(d1.x) + fabsf(d1.y) + fabsf(d1.z) + fabsf(d1.w);
                rsum += fabsf(d2.x) + fabsf(d2.y) + fabsf(d2.z) + fabsf(d2.w);
                rsum += fabsf(d3.x) + fabsf(d3.y) + fabsf(d3.z) + fabsf(d3.w);
            }
        }
#pragma unroll
        for (int r = 0; r < R; ++r) {
            const float4 xv = *(const float4*)(lds + r * FDIM + f0);
            acc[r].x += xv.x*d0.x + xv.y*d1.x + xv.z*d2.x + xv.w*d3.x;
            acc[r].y += xv.x*d0.y + xv.y*d1.y + xv.z*d2.y + xv.w*d3.y;
            acc[r].z += xv.x*d0.z + xv.y*d1.z + xv.z*d2.z + xv.w*d3.z;
            acc[r].w += xv.x*d0.w + xv.y*d1.w + xv.z*d2.w + xv.w*d3.w;
        }
    }

    // ---- reduce over the 4 f-groups inside each wave (lane bits 4,5)
#pragma unroll
    for (int r = 0; r < R; ++r) {
        acc[r].x += __shfl_xor(acc[r].x, 16, 64);
        acc[r].y += __shfl_xor(acc[r].y, 16, 64);
        acc[r].z += __shfl_xor(acc[r].z, 16, 64);
        acc[r].w += __shfl_xor(acc[r].w, 16, 64);
        acc[r].x += __shfl_xor(acc[r].x, 32, 64);
        acc[r].y += __shfl_xor(acc[r].y, 32, 64);
        acc[r].z += __shfl_xor(acc[r].z, 32, 64);
        acc[r].w += __shfl_xor(acc[r].w, 32, 64);
    }

    // ---- cross-wave reduction through LDS (aliases the x buffer)
    __syncthreads();                      // x reads done; reuse lds as red
    float* red = lds;                     // [(w*16+cq)][r*4+comp], padded stride
    const int RS = 4 * R + 4;             // per-(w,cq) stride in floats (pad)
    if ((tid & 63) < 16) {
#pragma unroll
        for (int r = 0; r < R; ++r)
            *(float4*)(red + (w * 16 + cq) * RS + r * 4) = acc[r];
    }
    __syncthreads();

    for (int idx = tid; idx < R * 64; idx += 256) {
        const int r = idx >> 6, c = idx & 63;
        float s = 0.f;
#pragma unroll
        for (int ww = 0; ww < 4; ++ww)
            s += red[(ww * 16 + (c >> 2)) * RS + r * 4 + (c & 3)];
        atomicAdd(out + (size_t)(b0 + r) * CDIM + c, s);
    }

    // ---- regularization: full wave butterfly + tiny LDS pass
#pragma unroll
    for (int off = 1; off < 64; off <<= 1) rsum += __shfl_xor(rsum, off, 64);
    __syncthreads();                      // red reads above finished
    if ((tid & 63) == 0) red[w] = rsum;
    __syncthreads();
    if (tid == 0 && regblk) {
        float t = red[0] + red[1] + red[2] + red[3];
        float scale = 1.f;
        if (!isroot) {
            const int p = (node - 1) >> 2;
            const float dist = fmaxf(fabsf(heights[node] - heights[p]), 1e-7f);
            scale = 1.f / dist;
        }
        atomicAdd(out + OUT_LOGITS, t * scale);
    }
}

__global__ __launch_bounds__(256) void k_main(const float* __restrict__ x,
                                              const float* __restrict__ deltas,
                                              const float* __restrict__ heights,
                                              float* __restrict__ out)
{
    __shared__ float lds[16 * FDIM];   // 32 KB (x tile; aliased as reduction buf)
    const int bid = blockIdx.x;
    const int tid = threadIdx.x;

    if (bid < 256) {
        int node, b0; bool rb;
        if (bid < 64)       { node = 0;                b0 = bid * 16;                      rb = (bid == 0); }
        else if (bid < 128) { const int q = bid - 64;  node = 1 + (q >> 4);
                              b0 = (q >> 4) * 256 + (q & 15) * 16;                         rb = (q & 15) == 0; }
        else if (bid < 192) { const int q = bid - 128; node = 5 + (q >> 2);
                              b0 = (q >> 2) * 64 + (q & 3) * 16;                           rb = (q & 3) == 0; }
        else                { const int q = bid - 192; node = 21 + q; b0 = q * 16;         rb = true; }
        run_tile<16>(x, deltas, heights, out, node, b0, rb, lds, tid);
    } else if (bid < 512) {
        const int q = bid - 256;
        run_tile<4>(x, deltas, heights, out, 85 + q, q * 4, true, lds, tid);
    } else {
        const int q = bid - 512;
        run_tile<1>(x, deltas, heights, out, 341 + q, q, true, lds, tid);
    }
}

// ---------------------------------------------------------------------------
// In-place softmax over C=64 per leaf row. One 64-lane wave per row.
// ---------------------------------------------------------------------------
__global__ __launch_bounds__(256) void k_softmax(float* __restrict__ out)
{
    const int b = blockIdx.x * 4 + (threadIdx.x >> 6);
    const int c = threadIdx.x & 63;
    const float v = out[(size_t)b * CDIM + c];
    float m = v;
#pragma unroll
    for (int off = 32; off > 0; off >>= 1) m = fmaxf(m, __shfl_xor(m, off, 64));
    const float e = expf(v - m);
    float s = e;
#pragma unroll
    for (int off = 32; off > 0; off >>= 1) s += __shfl_xor(s, off, 64);
    out[(size_t)b * CDIM + c] = e / s;
}

extern "C" void kernel_launch(void* const* d_in, const int* in_sizes, int n_in,
                              void* d_out, int out_size, void* d_ws, size_t ws_size,
                              hipStream_t stream)
{
    const float* x       = (const float*)d_in[0];
    const float* deltas  = (const float*)d_in[1];
    const float* heights = (const float*)d_in[2];
    float* out = (float*)d_out;

    hipMemsetAsync(out, 0, (size_t)(OUT_LOGITS + 1) * sizeof(float), stream);
    k_main<<<1536, 256, 0, stream>>>(x, deltas, heights, out);
    k_softmax<<<NLEAF / 4, 256, 0, stream>>>(out);
}

// Round 3
// 58.440 us; speedup vs baseline: 1.5375x; 1.0971x over previous
//
#include <hip/hip_runtime.h>

#define FDIM 512
#define CDIM 64
#define NLEAF 1024
#define MAT (FDIM * CDIM)          /* 32768 floats per node */
#define OUT_LOGITS (NLEAF * CDIM)  /* 65536 */

__device__ __forceinline__ float abs4(const float4 v) {
    return fabsf(v.x) + fabsf(v.y) + fabsf(v.z) + fabsf(v.w);
}
__device__ __forceinline__ float sq4(const float4 v) {
    return v.x * v.x + v.y * v.y + v.z * v.z + v.w * v.w;
}

// MODE: 0 = no reg accumulation, 1 = L1*scale, 2 = squared (root)
template<int MODE>
__device__ __forceinline__ void stream_node(const float* __restrict__ dbase,
                                            const float4* __restrict__ xr,
                                            float4& acc, float& rsum, float s)
{
#pragma unroll
    for (int ii = 0; ii < 8; ++ii) {
        const float* p = dbase + (size_t)ii * 4 * CDIM;
        const float4 d0 = *(const float4*)(p);
        const float4 d1 = *(const float4*)(p + CDIM);
        const float4 d2 = *(const float4*)(p + 2 * CDIM);
        const float4 d3 = *(const float4*)(p + 3 * CDIM);
        const float4 xv = xr[ii];
        acc.x += xv.x * d0.x + xv.y * d1.x + xv.z * d2.x + xv.w * d3.x;
        acc.y += xv.x * d0.y + xv.y * d1.y + xv.z * d2.y + xv.w * d3.y;
        acc.z += xv.x * d0.z + xv.y * d1.z + xv.z * d2.z + xv.w * d3.z;
        acc.w += xv.x * d0.w + xv.y * d1.w + xv.z * d2.w + xv.w * d3.w;
        if (MODE == 1) rsum = fmaf(abs4(d0) + abs4(d1) + abs4(d2) + abs4(d3), s, rsum);
        if (MODE == 2) rsum += sq4(d0) + sq4(d1) + sq4(d2) + sq4(d3);
    }
}

// ---------------------------------------------------------------------------
// One block per leaf: streams the 6 path deltas (768 KB) once, accumulating
// logits[64] split as (16 f-groups x 16 c-quads) across 256 threads, x slice
// held in registers. Fuses regularization + softmax. No atomics on logits.
// ---------------------------------------------------------------------------
__global__ __launch_bounds__(256, 4) void k_fused(const float* __restrict__ x,
                                                  const float* __restrict__ deltas,
                                                  const float* __restrict__ heights,
                                                  float* __restrict__ out,
                                                  float* __restrict__ ws)
{
    __shared__ float red[256 * 4];
    __shared__ float rred[4];

    const int bid = blockIdx.x;
    const int b   = ((bid & 7) << 7) | (bid >> 3);   // XCD-swizzled leaf id
    const int tid = threadIdx.x;
    const int fg  = tid >> 4;    // f-slice base = fg*32
    const int cq  = tid & 15;    // c-quad -> c = cq*4 .. cq*4+3

    float4 xr[8];
    {
        const float* xb = x + (size_t)b * FDIM + fg * 32;
#pragma unroll
        for (int i = 0; i < 8; ++i) xr[i] = *(const float4*)(xb + i * 4);
    }

    float4 acc = make_float4(0.f, 0.f, 0.f, 0.f);
    float rsum = 0.f;
    const size_t toff = (size_t)fg * 32 * CDIM + (size_t)cq * 4;

    // walk root -> leaf (co-resident blocks stay in phase for L2 reuse)
#pragma unroll
    for (int d = 0; d < 6; ++d) {
        const int shift = 2 * (5 - d);
        const int start = ((1 << (2 * d)) - 1) / 3;      // 0,1,5,21,85,341
        const int node  = start + (b >> shift);
        const float* dbase = deltas + (size_t)node * MAT + toff;
        const bool doReg = (b & ((1 << shift) - 1)) == 0;
        if (d == 0) {
            if (doReg) stream_node<2>(dbase, xr, acc, rsum, 1.f);
            else       stream_node<0>(dbase, xr, acc, rsum, 0.f);
        } else {
            if (doReg) {
                const int par = (node - 1) >> 2;
                const float s = 1.f / fmaxf(fabsf(heights[node] - heights[par]), 1e-7f);
                stream_node<1>(dbase, xr, acc, rsum, s);
            } else {
                stream_node<0>(dbase, xr, acc, rsum, 0.f);
            }
        }
    }

    // ---- logits: per-thread float4 partials -> LDS -> 64-lane reduce
    *(float4*)(red + tid * 4) = acc;      // flat index = fg*64 + cq*4 + j = fg*64 + c

    // ---- regularization partial: block reduce -> ws[bid]
#pragma unroll
    for (int off = 1; off < 64; off <<= 1) rsum += __shfl_xor(rsum, off, 64);
    if ((tid & 63) == 0) rred[tid >> 6] = rsum;
    __syncthreads();
    if (tid == 0) ws[bid] = rred[0] + rred[1] + rred[2] + rred[3];

    // ---- softmax on wave 0 (threads 0..63 hold logits c = tid)
    if (tid < CDIM) {
        float v = 0.f;
#pragma unroll
        for (int g = 0; g < 16; ++g) v += red[g * 64 + tid];
        float m = v;
#pragma unroll
        for (int off = 32; off > 0; off >>= 1) m = fmaxf(m, __shfl_xor(m, off, 64));
        const float e = expf(v - m);
        float s2 = e;
#pragma unroll
        for (int off = 32; off > 0; off >>= 1) s2 += __shfl_xor(s2, off, 64);
        out[(size_t)b * CDIM + tid] = e / s2;
    }
}

// ---------------------------------------------------------------------------
// Sum the 1024 per-block regularization partials -> out[OUT_LOGITS]
// ---------------------------------------------------------------------------
__global__ __launch_bounds__(256) void k_regsum(const float* __restrict__ ws,
                                                float* __restrict__ out)
{
    __shared__ float r[4];
    const int tid = threadIdx.x;
    float v = ws[tid] + ws[256 + tid] + ws[512 + tid] + ws[768 + tid];
#pragma unroll
    for (int off = 1; off < 64; off <<= 1) v += __shfl_xor(v, off, 64);
    if ((tid & 63) == 0) r[tid >> 6] = v;
    __syncthreads();
    if (tid == 0) out[OUT_LOGITS] = r[0] + r[1] + r[2] + r[3];
}

extern "C" void kernel_launch(void* const* d_in, const int* in_sizes, int n_in,
                              void* d_out, int out_size, void* d_ws, size_t ws_size,
                              hipStream_t stream)
{
    const float* x       = (const float*)d_in[0];
    const float* deltas  = (const float*)d_in[1];
    const float* heights = (const float*)d_in[2];
    float* out = (float*)d_out;
    float* ws  = (float*)d_ws;

    k_fused<<<NLEAF, 256, 0, stream>>>(x, deltas, heights, out, ws);
    k_regsum<<<1, 256, 0, stream>>>(ws, out);
}